// Round 12
// baseline (150.090 us; speedup 1.0000x reference)
//
#include <hip/hip_runtime.h>
#include <hip/hip_bf16.h>

#define FEAT   256
#define TROWS  16
#define TBYTES (TROWS * FEAT * 4)   // 16 KiB per x-tile
#define NBUF   3                    // depth-3: loads lead compute by 2 tiles

typedef __attribute__((ext_vector_type(8))) short  short8;
typedef __attribute__((ext_vector_type(4))) float  floatx4;

__device__ __forceinline__ short f2bf(float f) {
    __hip_bfloat16 h = __float2bfloat16(f);   // RTNE; pairs fuse to v_cvt_pk_bf16_f32
    return __builtin_bit_cast(short, h);
}

// Byte-offset swizzle within a 16-row tile: XOR bits 4..6 with row (=o>>10)&7.
// Involution, 16 B-granular. Applied to gload_lds SOURCE (dest linear) and
// to every LDS READ.
__device__ __forceinline__ unsigned swz(unsigned o) {
    return o ^ (((o >> 10) & 7u) << 4);
}

// R12 = R6 skeleton re-cut for 4 waves/SIMD (the untested winning cell):
//   - 8 waves x 32 cols (Bf[2][8] = 64 AGPR) -> total regs/wave ~124 <= 128
//     -> 4 waves/SIMD with __launch_bounds__(512,4), NO spill (R4 proved the
//     64 VGPR + 64 AGPR split compiles exactly).
//   - block = 512 thr stages one 16-row tile cooperatively (2 gload_lds/thr),
//     NBUF=3 (48 KiB), 2 blocks/CU = 16 waves/CU.
//   - counted vmcnt per wave (2 loads + 2 stores per iter):
//     steady: newer-than-L(it) = S(it-2)2 + L(it+1)2 + S(it-1)2 + L(it+2)2 = 8
//     -> vmcnt(8); it=0: 4; it=1: 6. Stores never drained.
//   - 4x/SIMD chain overlap is the lever R11 isolated as missing.
__global__ __launch_bounds__(512, 4) void gdn_kernel(
    const float* __restrict__ x,
    const float* __restrict__ beta,
    const float* __restrict__ gamma,
    float* __restrict__ out,
    int batch)
{
    __shared__ char ldsx[NBUF * TBYTES];   // 48 KiB -> 2 blocks/CU

    const int tid  = threadIdx.x;
    const int lane = tid & 63;
    const int wave = tid >> 6;          // 0..7 -> 32-col slice
    const int l15  = lane & 15;
    const int grp  = lane >> 4;
    const int colbase = wave * 32;

    // ---- One-time: gamma fragments (A-operand of swapped MFMA), 64 regs.
    // k-hat map k = ks*32 + grp*8 + i, shared by both operands (HW-verified:
    // R7/R9/R10/R11 all pass with this layout).
    short8 Bf[2][8];
    #pragma unroll
    for (int nt = 0; nt < 2; ++nt) {
        const int col = colbase + nt * 16 + l15;
        #pragma unroll
        for (int ks = 0; ks < 8; ++ks) {
            const int k0 = ks * 32 + grp * 8;
            short8 b;
            #pragma unroll
            for (int i = 0; i < 8; ++i)
                b[i] = f2bf(gamma[(size_t)(k0 + i) * FEAT + col]);
            Bf[nt][ks] = b;
        }
    }

    // beta_c per (nt, r): out-cols colbase + nt*16 + grp*4 + r
    floatx4 bc4[2];
    #pragma unroll
    for (int nt = 0; nt < 2; ++nt) {
        floatx4 b = *(const floatx4*)(beta + colbase + nt * 16 + grp * 4);
        #pragma unroll
        for (int r = 0; r < 4; ++r) bc4[nt][r] = fmaxf(b[r], 1e-6f);
    }

    const int ntiles = batch >> 4;      // 16384
    const int stride = gridDim.x;       // 512 -> exactly 32 iters/block
    const int iters  = ntiles / stride; // 32 (exact)
    const int t0     = blockIdx.x;

    // Cooperative stage of tile `t` into slot `s`: 512 thr x 2 x 16 B = 16 KiB.
    // Dest LINEAR (wave-uniform base + lane*16); source pre-swizzled.
    auto STAGE = [&](int s, int t) {
        const char* gb = (const char*)x + (size_t)t * TBYTES;
        char* lbase = &ldsx[s * TBYTES];
        #pragma unroll
        for (int r = 0; r < 2; ++r) {
            const unsigned d = (unsigned)(tid * 16 + r * 8192);
            __builtin_amdgcn_global_load_lds(
                (const __attribute__((address_space(1))) void*)(gb + swz(d)),
                (__attribute__((address_space(3))) void*)(lbase + d),
                16, 0, 0);
        }
    };

    // Prologue: 2 tiles in flight before first compute.
    STAGE(0, t0);
    STAGE(1, t0 + stride);

    const unsigned xv = (unsigned)((l15 & 7) << 4);
    const unsigned p0 = (unsigned)(l15 * 1024 + grp * 32);

    for (int it = 0; it < iters; ++it) {
        // Barrier A: every wave finished READING slot (it+2)%3 (at iter it-1).
        __builtin_amdgcn_s_barrier();
        __builtin_amdgcn_sched_barrier(0);

        int itn = it + 2;
        if (itn >= iters) itn = iters - 1;          // redundant tail re-stage
        STAGE((it + 2) % NBUF, t0 + itn * stride);  // slot-safe; never read

        // Wait ONLY for tile-it loads; newer loads AND stores stay in flight.
        if (it == 0)      asm volatile("s_waitcnt vmcnt(4)" ::: "memory");
        else if (it == 1) asm volatile("s_waitcnt vmcnt(6)" ::: "memory");
        else              asm volatile("s_waitcnt vmcnt(8)" ::: "memory");
        __builtin_amdgcn_sched_barrier(0);
        // Barrier B: all waves passed the wait -> tile-it fully in LDS.
        __builtin_amdgcn_s_barrier();
        __builtin_amdgcn_sched_barrier(0);

        const char* lb = &ldsx[(it % NBUF) * TBYTES];

        // ---- x^2 fragments (MFMA B-operand): row l15, k = ks*32+grp*8+i,
        // swizzled ds_read_b128 pairs (2-way banks = free).
        short8 Af[8];
        #pragma unroll
        for (int ks = 0; ks < 8; ++ks) {
            floatx4 v0 = *(const floatx4*)(lb + ((p0 + ks * 128)      ^ xv));
            floatx4 v1 = *(const floatx4*)(lb + ((p0 + ks * 128 + 16) ^ xv));
            short8 a;
            #pragma unroll
            for (int i = 0; i < 4; ++i) {
                a[i]     = f2bf(v0[i] * v0[i]);
                a[4 + i] = f2bf(v1[i] * v1[i]);
            }
            Af[ks] = a;
        }

        // ---- MFMA over K=256, swapped: D[out-col][x-row].
        // C/D: col(lane&15)=x-row, row(grp*4+r)=out-col (R7-verified).
        floatx4 acc[2] = {{0.f,0.f,0.f,0.f},{0.f,0.f,0.f,0.f}};
        #pragma unroll
        for (int ks = 0; ks < 8; ++ks) {
            acc[0] = __builtin_amdgcn_mfma_f32_16x16x32_bf16(Bf[0][ks], Af[ks], acc[0], 0, 0, 0);
            acc[1] = __builtin_amdgcn_mfma_f32_16x16x32_bf16(Bf[1][ks], Af[ks], acc[1], 0, 0, 0);
        }

        // ---- Epilogue: y = x * rsqrt(acc + beta_c); x from LDS (swizzled),
        // 2x ds_read_b128 + 2x global_store_dwordx4 per lane.
        const int rb = (t0 + it * stride) << 4;
        float* orow = out + (size_t)(rb + l15) * FEAT + colbase + grp * 4;
        #pragma unroll
        for (int nt = 0; nt < 2; ++nt) {
            const unsigned eo = (unsigned)(l15 * 1024 + (colbase + nt * 16 + grp * 4) * 4);
            floatx4 xval = *(const floatx4*)(lb + (eo ^ xv));
            floatx4 y;
            #pragma unroll
            for (int r = 0; r < 4; ++r)
                y[r] = xval[r] * rsqrtf(acc[nt][r] + bc4[nt][r]);
            *(floatx4*)(orow + nt * 16) = y;
        }
        // no drain: next iter's Barrier A needs only reg-held LDS reads done.
    }
}

extern "C" void kernel_launch(void* const* d_in, const int* in_sizes, int n_in,
                              void* d_out, int out_size, void* d_ws, size_t ws_size,
                              hipStream_t stream) {
    const float* x     = (const float*)d_in[0];
    const float* beta  = (const float*)d_in[1];
    const float* gamma = (const float*)d_in[2];
    float* out = (float*)d_out;

    const int batch = in_sizes[0] / FEAT;   // 262144

    dim3 grid(512);     // 2 blocks/CU (48 KiB LDS each), exactly 32 tiles each
    dim3 block(512);    // 8 waves x 32 cols -> 4 waves/SIMD, no spill
    hipLaunchKernelGGL(gdn_kernel, grid, block, 0, stream,
                       x, beta, gamma, out, batch);
}

// Round 13
// 145.849 us; speedup vs baseline: 1.0291x; 1.0291x over previous
//
#include <hip/hip_runtime.h>
#include <hip/hip_bf16.h>

#define FEAT  256
#define TROWS 16
#define PB    8192              // bytes per P buffer: 16 rows x 256 bf16

typedef __attribute__((ext_vector_type(8))) short  short8;
typedef __attribute__((ext_vector_type(4))) short  s16x4;
typedef __attribute__((ext_vector_type(4))) float  floatx4;

__device__ __forceinline__ short f2bf(float f) {
    __hip_bfloat16 h = __float2bfloat16(f);   // RTNE; pairs fuse to v_cvt_pk_bf16_f32
    return __builtin_bit_cast(short, h);
}

// R13: stage-thread == epilogue-thread (zero redistribution, cvt-once).
// Wave w owns cols [32w,32w+32). Lane (grp,l15) loads x[l15][32w+grp*4+{0..3}]
// and +16 cols into regs (q0,q1), squares+cvt -> 2x ds_write_b64 into shared
// bf16 P tile [row][k] (XOR-swizzled: addr ^= (row&7)<<4). ONE barrier. Every
// wave then ds_read_b128's its MFMA fragments from P (no per-wave cvt), 16
// MFMA (swapped: D[out-col][x-row], acc init = beta_c), epilogue multiplies
// the register-held x -> 2x global_store_dwordx4, then reloads q for tile
// it+2 (depth-2 slack ~ 1 full iter >= HBM latency; 4 waves/SIMD hide rest).
// P double-buffered (16 KiB): write(it+1) targets P[(it+1)&1] while reads(it)
// use P[it&1]; barrier(it+1) orders write(it+2) after all reads(it). No
// explicit vmcnt anywhere; stores never waited on.
__global__ __launch_bounds__(512, 4) void gdn_kernel(
    const float* __restrict__ x,
    const float* __restrict__ beta,
    const float* __restrict__ gamma,
    float* __restrict__ out,
    int batch)
{
    __shared__ char P[2 * PB];   // 16 KiB

    const int tid  = threadIdx.x;
    const int lane = tid & 63;
    const int wave = tid >> 6;          // 0..7 -> 32-col slice
    const int l15  = lane & 15;
    const int grp  = lane >> 4;
    const int colbase = wave * 32;

    // ---- One-time: gamma fragments (A-operand of swapped MFMA), 64 regs.
    // k-hat map k = ks*32 + grp*8 + i, shared by both operands (HW-verified:
    // R7/R9-R12 all pass with this layout).
    short8 Bf[2][8];
    #pragma unroll
    for (int nt = 0; nt < 2; ++nt) {
        const int col = colbase + nt * 16 + l15;
        #pragma unroll
        for (int ks = 0; ks < 8; ++ks) {
            const int k0 = ks * 32 + grp * 8;
            short8 b;
            #pragma unroll
            for (int i = 0; i < 8; ++i)
                b[i] = f2bf(gamma[(size_t)(k0 + i) * FEAT + col]);
            Bf[nt][ks] = b;
        }
    }

    // beta_c, folded into the accumulator init (D = A.B + C with C = beta_c).
    floatx4 bc0, bc1;
    {
        floatx4 b0 = *(const floatx4*)(beta + colbase + grp * 4);
        floatx4 b1 = *(const floatx4*)(beta + colbase + 16 + grp * 4);
        #pragma unroll
        for (int r = 0; r < 4; ++r) {
            bc0[r] = fmaxf(b0[r], 1e-6f);
            bc1[r] = fmaxf(b1[r], 1e-6f);
        }
    }

    const int stride = gridDim.x;                 // 512
    const int iters  = (batch / TROWS) / stride;  // 32 (exact, even)
    const int t0     = blockIdx.x;

    // Addressing. XOR-swizzle bits 4..6 of the k-byte offset with row&7;
    // row stride 512 B (bits >=9) and buffer offset PB (bit 13) are outside
    // the XOR field, so they add transparently.
    const unsigned xw  = (unsigned)((l15 & 7) << 4);
    const unsigned wb0 = (unsigned)((l15 * 512 + wave * 64 + grp * 8)      ^ xw);
    const unsigned wb1 = (unsigned)((l15 * 512 + wave * 64 + grp * 8 + 32) ^ xw);
    const unsigned rk  = (unsigned)(l15 * 512 + grp * 16);   // + ks*64, then ^xw

    const float* xb = x + (size_t)l15 * FEAT + colbase + grp * 4;

    auto ldq = [&](int it_idx, floatx4& q0, floatx4& q1) {
        const float* g = xb + (size_t)(t0 + it_idx * stride) * (TROWS * FEAT);
        q0 = ((const floatx4*)g)[0];
        q1 = ((const floatx4*)g)[4];    // +16 floats (cols +16)
    };

    auto body = [&](int it, floatx4& q0, floatx4& q1) {
        // ---- stage: x^2 -> bf16 -> P (2x ds_write_b64, swizzled)
        s16x4 s0, s1;
        #pragma unroll
        for (int i = 0; i < 4; ++i) {
            s0[i] = f2bf(q0[i] * q0[i]);
            s1[i] = f2bf(q1[i] * q1[i]);
        }
        char* Pb = P + (it & 1) * PB;
        *(s16x4*)(Pb + wb0) = s0;
        *(s16x4*)(Pb + wb1) = s1;

        // ---- one barrier: writes visible, prev-iter reads all retired
        asm volatile("s_waitcnt lgkmcnt(0)" ::: "memory");
        __builtin_amdgcn_sched_barrier(0);
        __builtin_amdgcn_s_barrier();
        __builtin_amdgcn_sched_barrier(0);

        // ---- MFMA over K=256: fragments straight from P (no cvt here).
        floatx4 acc0 = bc0, acc1 = bc1;
        #pragma unroll
        for (int ks = 0; ks < 8; ++ks) {
            short8 af = *(const short8*)(Pb + ((rk + ks * 64) ^ xw));
            acc0 = __builtin_amdgcn_mfma_f32_16x16x32_bf16(Bf[0][ks], af, acc0, 0, 0, 0);
            acc1 = __builtin_amdgcn_mfma_f32_16x16x32_bf16(Bf[1][ks], af, acc1, 0, 0, 0);
        }

        // ---- epilogue: y = x_reg * rsqrt(acc); acc already includes beta_c.
        const int rb = (t0 + it * stride) * TROWS;
        float* o = out + (size_t)(rb + l15) * FEAT + colbase + grp * 4;
        floatx4 y0, y1;
        #pragma unroll
        for (int r = 0; r < 4; ++r) {
            y0[r] = q0[r] * rsqrtf(acc0[r]);
            y1[r] = q1[r] * rsqrtf(acc1[r]);
        }
        ((floatx4*)o)[0] = y0;
        ((floatx4*)o)[4] = y1;

        // ---- reload this q pair for iteration it+2 (depth-2 slack)
        int tn = it + 2;
        if (tn >= iters) tn = iters - 1;   // redundant tail reload (harmless)
        ldq(tn, q0, q1);
    };

    // Prologue: two tiles of x in registers.
    floatx4 qA0, qA1, qB0, qB1;
    ldq(0, qA0, qA1);
    ldq(1, qB0, qB1);

    for (int it = 0; it < iters; it += 2) {
        body(it,     qA0, qA1);
        body(it + 1, qB0, qB1);
    }
}

extern "C" void kernel_launch(void* const* d_in, const int* in_sizes, int n_in,
                              void* d_out, int out_size, void* d_ws, size_t ws_size,
                              hipStream_t stream) {
    const float* x     = (const float*)d_in[0];
    const float* beta  = (const float*)d_in[1];
    const float* gamma = (const float*)d_in[2];
    float* out = (float*)d_out;

    const int batch = in_sizes[0] / FEAT;   // 262144

    dim3 grid(512);     // 2 blocks/CU, exactly 32 tiles each
    dim3 block(512);    // 8 waves x 32 cols; 4 waves/SIMD (16 waves/CU)
    hipLaunchKernelGGL(gdn_kernel, grid, block, 0, stream,
                       x, beta, gamma, out, batch);
}

// Round 14
// 116.645 us; speedup vs baseline: 1.2867x; 1.2504x over previous
//
#include <hip/hip_runtime.h>
#include <hip/hip_bf16.h>

#define FEAT   256
#define TROWS  16
#define TBYTES (TROWS * FEAT * 4)
#define NBUF   3
#define NFLAG  16          // detector blocks / flag words

typedef __attribute__((ext_vector_type(8))) short  short8;
typedef __attribute__((ext_vector_type(4))) float  floatx4;

__device__ __forceinline__ short f2bf(float f) {
    __hip_bfloat16 h = __float2bfloat16(f);
    return __builtin_bit_cast(short, h);
}

__device__ __forceinline__ unsigned swz(unsigned o) {
    return o ^ (((o >> 10) & 7u) << 4);
}

// ---------------- detector: is gamma diagonal? ----------------
// 16 blocks x 512 thr; block b checks rows [16b,16b+16). flags[b]=1 iff its
// slice has zero off-diagonals. Block 0 also extracts diag(gamma) and
// beta_c = max(beta,1e-6) into ws for the fast path.
__global__ __launch_bounds__(512) void gdn_detect(
    const float* __restrict__ gamma, const float* __restrict__ beta,
    int* __restrict__ flags, float* __restrict__ dws, float* __restrict__ bcws)
{
    int bad = 0;
    const int base = blockIdx.x * 16 * FEAT;
    for (int i = threadIdx.x; i < 16 * FEAT; i += 512) {
        const int idx = base + i;
        const int r = idx >> 8, c = idx & 255;
        const float v = gamma[idx];
        if (r != c && v != 0.0f) bad = 1;
    }
    __shared__ int s_ok[8];
    unsigned long long m = __ballot(bad);
    if ((threadIdx.x & 63) == 0) s_ok[threadIdx.x >> 6] = (m == 0ull);
    __syncthreads();
    if (threadIdx.x == 0) {
        int ok = 1;
        #pragma unroll
        for (int w = 0; w < 8; ++w) ok &= s_ok[w];
        flags[blockIdx.x] = ok;
    }
    if (blockIdx.x == 0 && threadIdx.x < FEAT) {
        dws[threadIdx.x]  = gamma[threadIdx.x * (FEAT + 1)];
        bcws[threadIdx.x] = fmaxf(beta[threadIdx.x], 1e-6f);
    }
}

// ---------------- fast path: diagonal gamma -> exact elementwise ----------------
// y[b,j] = x * rsqrt(d[j]*x^2 + bc[j]). Pure stream: float4 in, float4 out,
// contiguous per wave (the access shape the memory system runs at ~7 TB/s).
__global__ __launch_bounds__(256) void gdn_diag(
    const float* __restrict__ x, float* __restrict__ out,
    const int* __restrict__ flags, const float* __restrict__ dws,
    const float* __restrict__ bcws, int nvec4)
{
    int ok = 1;
    #pragma unroll
    for (int i = 0; i < NFLAG; ++i) ok &= flags[i];
    if (!ok) return;                      // dense gamma: other kernel handles

    // thread's float4 always covers cols (tid&63)*4 .. +3 (grid stride is a
    // multiple of 64 float4s), so d/bc load once.
    const int l = threadIdx.x & 63;
    const floatx4 d4 = *(const floatx4*)(dws + l * 4);
    const floatx4 b4 = *(const floatx4*)(bcws + l * 4);

    const size_t stride = (size_t)gridDim.x * blockDim.x;
    const floatx4* xv = (const floatx4*)x;
    floatx4*       ov = (floatx4*)out;
    for (size_t g = (size_t)blockIdx.x * blockDim.x + threadIdx.x;
         g < (size_t)nvec4; g += stride) {
        floatx4 v = xv[g];
        floatx4 y;
        #pragma unroll
        for (int i = 0; i < 4; ++i)
            y[i] = v[i] * rsqrtf(fmaf(d4[i] * v[i], v[i], b4[i]));
        ov[g] = y;
    }
}

// ---------------- general path: dense gamma (R6, best general kernel) ----------------
__global__ __launch_bounds__(256, 2) void gdn_kernel(
    const float* __restrict__ x,
    const float* __restrict__ beta,
    const float* __restrict__ gamma,
    float* __restrict__ out,
    int batch,
    const int* __restrict__ flags)       // null -> always run
{
    if (flags) {                          // early-exit if diagonal path ran
        int ok = 1;
        #pragma unroll
        for (int i = 0; i < NFLAG; ++i) ok &= flags[i];
        if (ok) return;
    }

    __shared__ char ldsx[NBUF * TBYTES];

    const int tid  = threadIdx.x;
    const int lane = tid & 63;
    const int wave = tid >> 6;
    const int l15  = lane & 15;
    const int grp  = lane >> 4;
    const int colbase = wave * 64;

    short8 Bf[4][8];
    #pragma unroll
    for (int nt = 0; nt < 4; ++nt) {
        const int col = colbase + nt * 16 + l15;
        #pragma unroll
        for (int ks = 0; ks < 8; ++ks) {
            const int k0 = ks * 32 + grp * 8;
            short8 b;
            #pragma unroll
            for (int i = 0; i < 8; ++i)
                b[i] = f2bf(gamma[(size_t)(k0 + i) * FEAT + col]);
            Bf[nt][ks] = b;
        }
    }

    float bc[4];
    #pragma unroll
    for (int nt = 0; nt < 4; ++nt)
        bc[nt] = fmaxf(beta[colbase + nt * 16 + l15], 1e-6f);

    const int ntiles = batch >> 4;
    const int stride = gridDim.x;
    const int iters  = ntiles / stride;
    const int t0     = blockIdx.x;

    auto STAGE = [&](int s, int t) {
        const char* gb = (const char*)x + (size_t)t * TBYTES;
        char* lbase = &ldsx[s * TBYTES];
        #pragma unroll
        for (int r = 0; r < 4; ++r) {
            const unsigned d = (unsigned)(tid * 16 + r * 4096);
            __builtin_amdgcn_global_load_lds(
                (const __attribute__((address_space(1))) void*)(gb + swz(d)),
                (__attribute__((address_space(3))) void*)(lbase + d),
                16, 0, 0);
        }
    };

    STAGE(0, t0);
    STAGE(1, t0 + stride);

    for (int it = 0; it < iters; ++it) {
        __builtin_amdgcn_s_barrier();
        __builtin_amdgcn_sched_barrier(0);

        int itn = it + 2;
        if (itn >= iters) itn = iters - 1;
        STAGE((it + 2) % NBUF, t0 + itn * stride);

        if (it == 0)      asm volatile("s_waitcnt vmcnt(8)"  ::: "memory");
        else if (it == 1) asm volatile("s_waitcnt vmcnt(12)" ::: "memory");
        else              asm volatile("s_waitcnt vmcnt(16)" ::: "memory");
        __builtin_amdgcn_sched_barrier(0);
        __builtin_amdgcn_s_barrier();
        __builtin_amdgcn_sched_barrier(0);

        const char* lb = &ldsx[(it % NBUF) * TBYTES];

        const unsigned p0 = (unsigned)(l15 * 1024 + grp * 32);
        const unsigned xv = (unsigned)((l15 & 7) << 4);
        short8 Af[8];
        #pragma unroll
        for (int ks = 0; ks < 8; ++ks) {
            floatx4 v0 = *(const floatx4*)(lb + ((p0 + ks * 128)      ^ xv));
            floatx4 v1 = *(const floatx4*)(lb + ((p0 + ks * 128 + 16) ^ xv));
            short8 a;
            #pragma unroll
            for (int i = 0; i < 4; ++i) {
                a[i]     = f2bf(v0[i] * v0[i]);
                a[4 + i] = f2bf(v1[i] * v1[i]);
            }
            Af[ks] = a;
        }

        floatx4 acc[4] = {{0.f,0.f,0.f,0.f},{0.f,0.f,0.f,0.f},
                          {0.f,0.f,0.f,0.f},{0.f,0.f,0.f,0.f}};
        #pragma unroll
        for (int ks = 0; ks < 8; ++ks) {
            #pragma unroll
            for (int nt = 0; nt < 4; ++nt) {
                acc[nt] = __builtin_amdgcn_mfma_f32_16x16x32_bf16(
                    Af[ks], Bf[nt][ks], acc[nt], 0, 0, 0);
            }
        }

        const int rb = (t0 + it * stride) << 4;
        #pragma unroll
        for (int nt = 0; nt < 4; ++nt) {
            const int col = colbase + nt * 16 + l15;
            #pragma unroll
            for (int r = 0; r < 4; ++r) {
                const int row = grp * 4 + r;
                const unsigned eo = (unsigned)(row * 1024 + col * 4);
                const float xval = *(const float*)(lb + (eo ^ (((unsigned)(row & 7)) << 4)));
                out[(size_t)(rb + row) * FEAT + col] = xval * rsqrtf(acc[nt][r] + bc[nt]);
            }
        }
    }
}

extern "C" void kernel_launch(void* const* d_in, const int* in_sizes, int n_in,
                              void* d_out, int out_size, void* d_ws, size_t ws_size,
                              hipStream_t stream) {
    const float* x     = (const float*)d_in[0];
    const float* beta  = (const float*)d_in[1];
    const float* gamma = (const float*)d_in[2];
    float* out = (float*)d_out;

    const int batch = in_sizes[0] / FEAT;   // 262144
    const int nvec4 = (batch * FEAT) / 4;   // 16,777,216

    if (ws_size >= 4096) {
        int*   flags = (int*)d_ws;                          // 16 ints
        float* dws   = (float*)((char*)d_ws + 1024);        // 256 f32
        float* bcws  = (float*)((char*)d_ws + 2048);        // 256 f32

        hipLaunchKernelGGL(gdn_detect, dim3(NFLAG), dim3(512), 0, stream,
                           gamma, beta, flags, dws, bcws);
        hipLaunchKernelGGL(gdn_diag, dim3(2048), dim3(256), 0, stream,
                           x, out, flags, dws, bcws, nvec4);
        hipLaunchKernelGGL(gdn_kernel, dim3(512), dim3(256), 0, stream,
                           x, beta, gamma, out, batch, flags);
    } else {
        hipLaunchKernelGGL(gdn_kernel, dim3(512), dim3(256), 0, stream,
                           x, beta, gamma, out, batch, (const int*)nullptr);
    }
}